// Round 8
// baseline (438.073 us; speedup 1.0000x reference)
//
#include <hip/hip_runtime.h>
#include <float.h>
#include <limits.h>

// N=131072, K=2048, D=64.
// Verified reference scheme R (rounds 5/7, absmax 0.0):
//   xsq: numpy NPY_SIMD-128 pairwise (8 vec-accs x 4 lanes + SSE3 hadd tree)
//   esq: scalar pairwise-8; dot: any fp32 order; dist=fl(fl(xsq+esq)-2dot);
//   argmin first-index.
// Round 8 = round 7 algorithm (MFMA screen + margin candidates + exact
// rescore + lossless overflow fallback), re-engineered for latency:
//   - screen loops software-pipelined (prefetch next B-tile + esq)
//   - esq out of LDS (global L2 reads), CAP 64->32, rowmin overlaid on cand
//     region => LDS ~25.9 KB => 6 blocks/CU (was 3)
//   - overflow fallback now block-cooperative (256 threads/row, ~1us) so
//     CAP 32 stays provably lossless and cheap.
#define D_DIM 64
#define K_CB  2048
#define BM    64
#define CT_PER_WAVE 32          // 16-code tiles per wave (4 waves x 512 codes)
#define MARGIN 2.5e-3f
#define CAND_CAP 32

typedef __attribute__((ext_vector_type(4))) float f32x4;
typedef __attribute__((ext_vector_type(8))) short s16x8;

__device__ __forceinline__ short f2bf(float f) {   // RN-even fp32->bf16 bits
  unsigned u = __builtin_bit_cast(unsigned, f);
  u += 0x7fffu + ((u >> 16) & 1u);
  return (short)(unsigned short)(u >> 16);
}

// prep: esq[k] (scalar-8 numpy order, verified) + bf16 codebook for MFMA
__global__ void __launch_bounds__(256) prep_kernel(const float* __restrict__ cb,
                                                   float* __restrict__ esq,
                                                   unsigned short* __restrict__ cbh) {
#pragma clang fp contract(off)
  int k = blockIdx.x * 256 + threadIdx.x;
  if (k >= K_CB) return;
  const float* row = cb + (size_t)k * D_DIM;
  float r[8];
#pragma unroll
  for (int j = 0; j < 8; ++j) { float v = row[j]; r[j] = v * v; }
#pragma unroll
  for (int i = 1; i < 8; ++i)
#pragma unroll
    for (int j = 0; j < 8; ++j) { float v = row[8 * i + j]; r[j] += v * v; }
  esq[k] = ((r[0] + r[1]) + (r[2] + r[3])) + ((r[4] + r[5]) + (r[6] + r[7]));
  unsigned short* o = cbh + (size_t)k * D_DIM;
#pragma unroll
  for (int j = 0; j < D_DIM; ++j) o[j] = (unsigned short)f2bf(row[j]);
}

__global__ void __launch_bounds__(256, 6)
vq_mfma_kernel(const float* __restrict__ x,
               const float* __restrict__ cb,
               const float* __restrict__ esq,
               const unsigned short* __restrict__ cbh,
               float* __restrict__ out) {
#pragma clang fp contract(off)
  __shared__ float4 xs4[BM * 16];          // 16 KB x tile, float4-XOR swizzled
  __shared__ int    cand_s[BM * CAND_CAP]; // 8 KB; overlaid: rowmin (pass1),
                                           //   fallback reduce scratch (end)
  __shared__ float  xsq_s[BM];
  __shared__ float  rowthr_s[BM];
  __shared__ int    cnt_s[BM];
  __shared__ int    bestk_s[BM];
  __shared__ int    ovf_rows[BM];
  __shared__ int    ovf_cnt;

  const int tid  = threadIdx.x;
  const int lane = tid & 63;
  const int wave = tid >> 6;
  const int row0 = blockIdx.x * BM;

  // ---- stage x tile (coalesced float4), swizzle float4-col ^= (row>>2)&7 ----
  const float4* xg = (const float4*)(x + (size_t)row0 * D_DIM);
#pragma unroll
  for (int i = 0; i < 4; ++i) {
    int f = tid + i * 256;
    int row = f >> 4, c4 = f & 15;
    xs4[row * 16 + (c4 ^ ((row >> 2) & 7))] = xg[f];
  }
  if (tid == 0) ovf_cnt = 0;
  __syncthreads();

  // ---- xsq per row: numpy NPY_SIMD-128 pairwise emulation (verified R5) ----
  if (tid < BM) {
    const int swz = 4 * ((tid >> 2) & 7);
    const float* xr = (const float*)xs4 + tid * 64;
    float s[4];
#pragma unroll
    for (int l = 0; l < 4; ++l) {
      float rj[8];
#pragma unroll
      for (int j = 0; j < 8; ++j) {
        float a = xr[(4 * j + l) ^ swz];
        float b = xr[(32 + 4 * j + l) ^ swz];
        float ta = a * a;
        float tb = b * b;
        rj[j] = ta + tb;
      }
      s[l] = ((rj[0] + rj[1]) + (rj[2] + rj[3])) +
             ((rj[4] + rj[5]) + (rj[6] + rj[7]));
    }
    xsq_s[tid] = (s[0] + s[1]) + (s[2] + s[3]);
  }

  // ---- A fragments (x rows in bf16), resident in regs.  16x16x32:
  //   A: lane holds row=lane&15, k=(lane>>4)*8+j ; B: col=lane&15, same k;
  //   C: col=lane&15, row=(lane>>4)*4+reg  (m89-verified).
  s16x8 afrag[4][2];
  {
    const int arow = lane & 15;
    const int kg = (lane >> 4) * 8;
#pragma unroll
    for (int rt = 0; rt < 4; ++rt) {
      int row = rt * 16 + arow;
      int sw = (row >> 2) & 7;
#pragma unroll
      for (int kt = 0; kt < 2; ++kt) {
        int q0 = (kt * 32 + kg) >> 2;
        float4 f0 = xs4[row * 16 + (q0 ^ sw)];
        float4 f1 = xs4[row * 16 + ((q0 + 1) ^ sw)];
        s16x8 a;
        a[0] = f2bf(f0.x); a[1] = f2bf(f0.y); a[2] = f2bf(f0.z); a[3] = f2bf(f0.w);
        a[4] = f2bf(f1.x); a[5] = f2bf(f1.y); a[6] = f2bf(f1.z); a[7] = f2bf(f1.w);
        afrag[rt][kt] = a;
      }
    }
  }

  const int cbase = wave * (CT_PER_WAVE * 16);
  const int ccol = lane & 15;
  const int kgrp = (lane >> 4) * 8;

  // ================= pass 1: per-row screen min (pipelined) =================
  float minv[4][4];
#pragma unroll
  for (int rt = 0; rt < 4; ++rt)
#pragma unroll
    for (int r = 0; r < 4; ++r) minv[rt][r] = FLT_MAX;

  {
    int kbase = cbase;
    const unsigned short* bp = cbh + (size_t)(kbase + ccol) * D_DIM + kgrp;
    s16x8 b0 = *(const s16x8*)bp;
    s16x8 b1 = *(const s16x8*)(bp + 32);
    float ec = esq[kbase + ccol];
    for (int ct = 0; ct < CT_PER_WAVE; ++ct) {
      int nkbase = cbase + (((ct + 1) & (CT_PER_WAVE - 1)) << 4);
      const unsigned short* nbp = cbh + (size_t)(nkbase + ccol) * D_DIM + kgrp;
      s16x8 nb0 = *(const s16x8*)nbp;
      s16x8 nb1 = *(const s16x8*)(nbp + 32);
      float nec = esq[nkbase + ccol];
#pragma unroll
      for (int rt = 0; rt < 4; ++rt) {
        f32x4 acc = {0.f, 0.f, 0.f, 0.f};
        acc = __builtin_amdgcn_mfma_f32_16x16x32_bf16(afrag[rt][0], b0, acc, 0, 0, 0);
        acc = __builtin_amdgcn_mfma_f32_16x16x32_bf16(afrag[rt][1], b1, acc, 0, 0, 0);
#pragma unroll
        for (int r = 0; r < 4; ++r) {
          float s = fmaf(-2.0f, acc[r], ec);   // == fl(ec - 2*acc): 2*acc exact
          minv[rt][r] = fminf(minv[rt][r], s);
        }
      }
      b0 = nb0; b1 = nb1; ec = nec;
    }
  }

  // cross-lane min within the 16 cols; rowmin overlaid at front of cand_s
  float* rowmin = (float*)cand_s;        // [4 waves][BM]
#pragma unroll
  for (int rt = 0; rt < 4; ++rt)
#pragma unroll
    for (int r = 0; r < 4; ++r) {
      float v = minv[rt][r];
#pragma unroll
      for (int m = 1; m <= 8; m <<= 1) v = fminf(v, __shfl_xor(v, m));
      minv[rt][r] = v;
    }
  if ((lane & 15) == 0) {
#pragma unroll
    for (int rt = 0; rt < 4; ++rt)
#pragma unroll
      for (int r = 0; r < 4; ++r)
        rowmin[wave * BM + rt * 16 + (lane >> 4) * 4 + r] = minv[rt][r];
  }
  __syncthreads();
  if (tid < BM) {
    float m = fminf(fminf(rowmin[0 * BM + tid], rowmin[1 * BM + tid]),
                    fminf(rowmin[2 * BM + tid], rowmin[3 * BM + tid]));
    rowthr_s[tid] = m + MARGIN;
    cnt_s[tid] = 0;
  }
  __syncthreads();

  float thr[4][4];
#pragma unroll
  for (int rt = 0; rt < 4; ++rt)
#pragma unroll
    for (int r = 0; r < 4; ++r)
      thr[rt][r] = rowthr_s[rt * 16 + (lane >> 4) * 4 + r];

  // ====== pass 2: recompute (bit-identical), collect candidates ======
  {
    int kbase = cbase;
    const unsigned short* bp = cbh + (size_t)(kbase + ccol) * D_DIM + kgrp;
    s16x8 b0 = *(const s16x8*)bp;
    s16x8 b1 = *(const s16x8*)(bp + 32);
    float ec = esq[kbase + ccol];
    for (int ct = 0; ct < CT_PER_WAVE; ++ct) {
      int nkbase = cbase + (((ct + 1) & (CT_PER_WAVE - 1)) << 4);
      const unsigned short* nbp = cbh + (size_t)(nkbase + ccol) * D_DIM + kgrp;
      s16x8 nb0 = *(const s16x8*)nbp;
      s16x8 nb1 = *(const s16x8*)(nbp + 32);
      float nec = esq[nkbase + ccol];
#pragma unroll
      for (int rt = 0; rt < 4; ++rt) {
        f32x4 acc = {0.f, 0.f, 0.f, 0.f};
        acc = __builtin_amdgcn_mfma_f32_16x16x32_bf16(afrag[rt][0], b0, acc, 0, 0, 0);
        acc = __builtin_amdgcn_mfma_f32_16x16x32_bf16(afrag[rt][1], b1, acc, 0, 0, 0);
#pragma unroll
        for (int r = 0; r < 4; ++r) {
          float s = fmaf(-2.0f, acc[r], ec);
          if (s <= thr[rt][r]) {
            int row = rt * 16 + (lane >> 4) * 4 + r;
            int pos = atomicAdd(&cnt_s[row], 1);
            if (pos < CAND_CAP) cand_s[row * CAND_CAP + pos] = kbase + ccol;
          }
        }
      }
      b0 = nb0; b1 = nb1; ec = nec; kbase = nkbase;
    }
  }
  __syncthreads();

  // ====== exact rescore (R-scheme), lex-(dist,k); 4 threads per row ======
  {
    const int row = tid >> 2, slot = tid & 3;
    const int cnt = cnt_s[row];
    if (cnt <= CAND_CAP) {
      const int swz = 4 * ((row >> 2) & 7);
      const float* xr = (const float*)xs4 + row * 64;
      const float xq = xsq_s[row];
      float bv = FLT_MAX; int bk = INT_MAX;
      for (int i = slot; i < cnt; i += 4) {
        int k = cand_s[row * CAND_CAP + i];
        const float* er = cb + (size_t)k * D_DIM;
        float a = 0.f;
#pragma unroll 8
        for (int d = 0; d < D_DIM; ++d) a = fmaf(xr[d ^ swz], er[d], a);
        float dist = (xq + esq[k]) - 2.0f * a;
        if (dist < bv || (dist == bv && k < bk)) { bv = dist; bk = k; }
      }
#pragma unroll
      for (int m = 1; m <= 2; m <<= 1) {
        float ov = __shfl_xor(bv, m); int ok = __shfl_xor(bk, m);
        if (ov < bv || (ov == bv && ok < bk)) { bv = ov; bk = ok; }
      }
      if (slot == 0) bestk_s[row] = bk;
    }
  }
  if (tid < BM && cnt_s[tid] > CAND_CAP) {
    int p = atomicAdd(&ovf_cnt, 1);
    ovf_rows[p] = tid;
  }
  __syncthreads();

  // ====== lossless overflow fallback: block-cooperative full scan ======
  {
    const int novf = ovf_cnt;
    float* fv = (float*)cand_s;          // scratch (cand no longer needed)
    int*   fk = (int*)cand_s + 8;
    for (int i = 0; i < novf; ++i) {
      const int row = ovf_rows[i];
      const int swz = 4 * ((row >> 2) & 7);
      const float* xr = (const float*)xs4 + row * 64;
      const float xq = xsq_s[row];
      float bv = FLT_MAX; int bk = INT_MAX;
      for (int k = tid; k < K_CB; k += 256) {
        const float* er = cb + (size_t)k * D_DIM;
        float a = 0.f;
#pragma unroll 8
        for (int d = 0; d < D_DIM; ++d) a = fmaf(xr[d ^ swz], er[d], a);
        float dist = (xq + esq[k]) - 2.0f * a;
        if (dist < bv || (dist == bv && k < bk)) { bv = dist; bk = k; }
      }
#pragma unroll
      for (int m = 1; m <= 32; m <<= 1) {
        float ov = __shfl_xor(bv, m); int ok = __shfl_xor(bk, m);
        if (ov < bv || (ov == bv && ok < bk)) { bv = ov; bk = ok; }
      }
      if (lane == 0) { fv[wave] = bv; fk[wave] = bk; }
      __syncthreads();
      if (tid == 0) {
        float BV = fv[0]; int BK = fk[0];
#pragma unroll
        for (int w = 1; w < 4; ++w)
          if (fv[w] < BV || (fv[w] == BV && fk[w] < BK)) { BV = fv[w]; BK = fk[w]; }
        bestk_s[row] = BK;
      }
      __syncthreads();
    }
  }
  __syncthreads();

  // ---- gather: out[row] = codebook[bestk[row]], coalesced float4 ----
  const float4* cb4 = (const float4*)cb;
  float4* out4 = (float4*)out + (size_t)row0 * 16;
#pragma unroll
  for (int i = 0; i < 4; ++i) {
    int f = tid + i * 256;
    int row = f >> 4, c4 = f & 15;
    out4[f] = cb4[(size_t)bestk_s[row] * 16 + c4];
  }
}

extern "C" void kernel_launch(void* const* d_in, const int* in_sizes, int n_in,
                              void* d_out, int out_size, void* d_ws, size_t ws_size,
                              hipStream_t stream) {
  const float* x  = (const float*)d_in[0];   // [N, 64] fp32
  const float* cb = (const float*)d_in[1];   // [2048, 64] fp32
  float* out = (float*)d_out;                // [N, 64] fp32
  float* esq = (float*)d_ws;                 // [2048] fp32
  unsigned short* cbh = (unsigned short*)d_ws + 4096;  // bf16 codebook, 256 KB

  const int N = in_sizes[0] / D_DIM;         // 131072

  prep_kernel<<<(K_CB + 255) / 256, 256, 0, stream>>>(cb, esq, cbh);
  vq_mfma_kernel<<<N / BM, 256, 0, stream>>>(x, cb, esq, cbh, out);
}

// Round 9
// 239.028 us; speedup vs baseline: 1.8327x; 1.8327x over previous
//
#include <hip/hip_runtime.h>
#include <float.h>
#include <limits.h>

// N=131072, K=2048, D=64.
// Verified reference scheme R (rounds 5/7/8, absmax 0.0):
//   xsq: numpy NPY_SIMD-128 pairwise (8 vec-accs x 4 lanes + SSE3 hadd tree)
//   esq: scalar pairwise-8; dot: any fp32 order; dist=fl(fl(xsq+esq)-2dot);
//   argmin first-index.
// Round 9: round-7 simple (non-pipelined) screen loops — compiler schedules
// the independent dwordx4 B-loads fine at 68 VGPR — combined with round-8's
// LDS diet (esq from global L2, CAP 32, rowmin overlaid on cand_s => ~25.5 KB
// => 6 blocks/CU) and the block-cooperative lossless overflow fallback.
// NO min-waves launch-bounds clause: round 8's (256,6) forced a 40-VGPR
// budget and spilled to scratch (FETCH 157 MB / WRITE 228 MB observed).
#define D_DIM 64
#define K_CB  2048
#define BM    64
#define CT_PER_WAVE 32          // 16-code tiles per wave (4 waves x 512 codes)
#define MARGIN 2.5e-3f
#define CAND_CAP 32

typedef __attribute__((ext_vector_type(4))) float f32x4;
typedef __attribute__((ext_vector_type(8))) short s16x8;

__device__ __forceinline__ short f2bf(float f) {   // RN-even fp32->bf16 bits
  unsigned u = __builtin_bit_cast(unsigned, f);
  u += 0x7fffu + ((u >> 16) & 1u);
  return (short)(unsigned short)(u >> 16);
}

// prep: esq[k] (scalar-8 numpy order, verified) + bf16 codebook for MFMA
__global__ void __launch_bounds__(256) prep_kernel(const float* __restrict__ cb,
                                                   float* __restrict__ esq,
                                                   unsigned short* __restrict__ cbh) {
#pragma clang fp contract(off)
  int k = blockIdx.x * 256 + threadIdx.x;
  if (k >= K_CB) return;
  const float* row = cb + (size_t)k * D_DIM;
  float r[8];
#pragma unroll
  for (int j = 0; j < 8; ++j) { float v = row[j]; r[j] = v * v; }
#pragma unroll
  for (int i = 1; i < 8; ++i)
#pragma unroll
    for (int j = 0; j < 8; ++j) { float v = row[8 * i + j]; r[j] += v * v; }
  esq[k] = ((r[0] + r[1]) + (r[2] + r[3])) + ((r[4] + r[5]) + (r[6] + r[7]));
  unsigned short* o = cbh + (size_t)k * D_DIM;
#pragma unroll
  for (int j = 0; j < D_DIM; ++j) o[j] = (unsigned short)f2bf(row[j]);
}

__global__ void __launch_bounds__(256)
vq_mfma_kernel(const float* __restrict__ x,
               const float* __restrict__ cb,
               const float* __restrict__ esq,
               const unsigned short* __restrict__ cbh,
               float* __restrict__ out) {
#pragma clang fp contract(off)
  __shared__ float4 xs4[BM * 16];          // 16 KB x tile, float4-XOR swizzled
  __shared__ int    cand_s[BM * CAND_CAP]; // 8 KB; overlaid: rowmin (pass1),
                                           //   fallback reduce scratch (end)
  __shared__ float  xsq_s[BM];
  __shared__ float  rowthr_s[BM];
  __shared__ int    cnt_s[BM];
  __shared__ int    bestk_s[BM];
  __shared__ int    ovf_rows[BM];
  __shared__ int    ovf_cnt;

  const int tid  = threadIdx.x;
  const int lane = tid & 63;
  const int wave = tid >> 6;
  const int row0 = blockIdx.x * BM;

  // ---- stage x tile (coalesced float4), swizzle float4-col ^= (row>>2)&7 ----
  const float4* xg = (const float4*)(x + (size_t)row0 * D_DIM);
#pragma unroll
  for (int i = 0; i < 4; ++i) {
    int f = tid + i * 256;
    int row = f >> 4, c4 = f & 15;
    xs4[row * 16 + (c4 ^ ((row >> 2) & 7))] = xg[f];
  }
  if (tid == 0) ovf_cnt = 0;
  __syncthreads();

  // ---- xsq per row: numpy NPY_SIMD-128 pairwise emulation (verified R5) ----
  if (tid < BM) {
    const int swz = 4 * ((tid >> 2) & 7);
    const float* xr = (const float*)xs4 + tid * 64;
    float s[4];
#pragma unroll
    for (int l = 0; l < 4; ++l) {
      float rj[8];
#pragma unroll
      for (int j = 0; j < 8; ++j) {
        float a = xr[(4 * j + l) ^ swz];
        float b = xr[(32 + 4 * j + l) ^ swz];
        float ta = a * a;
        float tb = b * b;
        rj[j] = ta + tb;
      }
      s[l] = ((rj[0] + rj[1]) + (rj[2] + rj[3])) +
             ((rj[4] + rj[5]) + (rj[6] + rj[7]));
    }
    xsq_s[tid] = (s[0] + s[1]) + (s[2] + s[3]);
  }

  // ---- A fragments (x rows in bf16), resident in regs.  16x16x32:
  //   A: lane holds row=lane&15, k=(lane>>4)*8+j ; B: col=lane&15, same k;
  //   C: col=lane&15, row=(lane>>4)*4+reg  (m89-verified).
  s16x8 afrag[4][2];
  {
    const int arow = lane & 15;
    const int kg = (lane >> 4) * 8;
#pragma unroll
    for (int rt = 0; rt < 4; ++rt) {
      int row = rt * 16 + arow;
      int sw = (row >> 2) & 7;
#pragma unroll
      for (int kt = 0; kt < 2; ++kt) {
        int q0 = (kt * 32 + kg) >> 2;
        float4 f0 = xs4[row * 16 + (q0 ^ sw)];
        float4 f1 = xs4[row * 16 + ((q0 + 1) ^ sw)];
        s16x8 a;
        a[0] = f2bf(f0.x); a[1] = f2bf(f0.y); a[2] = f2bf(f0.z); a[3] = f2bf(f0.w);
        a[4] = f2bf(f1.x); a[5] = f2bf(f1.y); a[6] = f2bf(f1.z); a[7] = f2bf(f1.w);
        afrag[rt][kt] = a;
      }
    }
  }

  const int cbase = wave * (CT_PER_WAVE * 16);
  const int ccol = lane & 15;
  const int kgrp = (lane >> 4) * 8;

  // ================= pass 1: per-row screen min =================
  float minv[4][4];
#pragma unroll
  for (int rt = 0; rt < 4; ++rt)
#pragma unroll
    for (int r = 0; r < 4; ++r) minv[rt][r] = FLT_MAX;

  for (int ct = 0; ct < CT_PER_WAVE; ++ct) {
    int code0 = cbase + ct * 16;
    const unsigned short* bp = cbh + (size_t)(code0 + ccol) * D_DIM + kgrp;
    s16x8 b0 = *(const s16x8*)bp;
    s16x8 b1 = *(const s16x8*)(bp + 32);
    float ec = esq[code0 + ccol];
#pragma unroll
    for (int rt = 0; rt < 4; ++rt) {
      f32x4 acc = {0.f, 0.f, 0.f, 0.f};
      acc = __builtin_amdgcn_mfma_f32_16x16x32_bf16(afrag[rt][0], b0, acc, 0, 0, 0);
      acc = __builtin_amdgcn_mfma_f32_16x16x32_bf16(afrag[rt][1], b1, acc, 0, 0, 0);
#pragma unroll
      for (int r = 0; r < 4; ++r) {
        float s = fmaf(-2.0f, acc[r], ec);   // == fl(ec - 2*acc): 2*acc exact
        minv[rt][r] = fminf(minv[rt][r], s);
      }
    }
  }

  // cross-lane min within the 16 cols; rowmin overlaid at front of cand_s
  float* rowmin = (float*)cand_s;        // [4 waves][BM]
#pragma unroll
  for (int rt = 0; rt < 4; ++rt)
#pragma unroll
    for (int r = 0; r < 4; ++r) {
      float v = minv[rt][r];
#pragma unroll
      for (int m = 1; m <= 8; m <<= 1) v = fminf(v, __shfl_xor(v, m));
      minv[rt][r] = v;
    }
  if ((lane & 15) == 0) {
#pragma unroll
    for (int rt = 0; rt < 4; ++rt)
#pragma unroll
      for (int r = 0; r < 4; ++r)
        rowmin[wave * BM + rt * 16 + (lane >> 4) * 4 + r] = minv[rt][r];
  }
  __syncthreads();
  if (tid < BM) {
    float m = fminf(fminf(rowmin[0 * BM + tid], rowmin[1 * BM + tid]),
                    fminf(rowmin[2 * BM + tid], rowmin[3 * BM + tid]));
    rowthr_s[tid] = m + MARGIN;
    cnt_s[tid] = 0;
  }
  __syncthreads();

  float thr[4][4];
#pragma unroll
  for (int rt = 0; rt < 4; ++rt)
#pragma unroll
    for (int r = 0; r < 4; ++r)
      thr[rt][r] = rowthr_s[rt * 16 + (lane >> 4) * 4 + r];

  // ====== pass 2: recompute (bit-identical), collect candidates ======
  for (int ct = 0; ct < CT_PER_WAVE; ++ct) {
    int code0 = cbase + ct * 16;
    const unsigned short* bp = cbh + (size_t)(code0 + ccol) * D_DIM + kgrp;
    s16x8 b0 = *(const s16x8*)bp;
    s16x8 b1 = *(const s16x8*)(bp + 32);
    float ec = esq[code0 + ccol];
#pragma unroll
    for (int rt = 0; rt < 4; ++rt) {
      f32x4 acc = {0.f, 0.f, 0.f, 0.f};
      acc = __builtin_amdgcn_mfma_f32_16x16x32_bf16(afrag[rt][0], b0, acc, 0, 0, 0);
      acc = __builtin_amdgcn_mfma_f32_16x16x32_bf16(afrag[rt][1], b1, acc, 0, 0, 0);
#pragma unroll
      for (int r = 0; r < 4; ++r) {
        float s = fmaf(-2.0f, acc[r], ec);
        if (s <= thr[rt][r]) {
          int row = rt * 16 + (lane >> 4) * 4 + r;
          int pos = atomicAdd(&cnt_s[row], 1);
          if (pos < CAND_CAP) cand_s[row * CAND_CAP + pos] = code0 + ccol;
        }
      }
    }
  }
  __syncthreads();

  // ====== exact rescore (R-scheme), lex-(dist,k); 4 threads per row ======
  {
    const int row = tid >> 2, slot = tid & 3;
    const int cnt = cnt_s[row];
    if (cnt <= CAND_CAP) {
      const int swz = 4 * ((row >> 2) & 7);
      const float* xr = (const float*)xs4 + row * 64;
      const float xq = xsq_s[row];
      float bv = FLT_MAX; int bk = INT_MAX;
      for (int i = slot; i < cnt; i += 4) {
        int k = cand_s[row * CAND_CAP + i];
        const float* er = cb + (size_t)k * D_DIM;
        float a = 0.f;
#pragma unroll 8
        for (int d = 0; d < D_DIM; ++d) a = fmaf(xr[d ^ swz], er[d], a);
        float dist = (xq + esq[k]) - 2.0f * a;
        if (dist < bv || (dist == bv && k < bk)) { bv = dist; bk = k; }
      }
#pragma unroll
      for (int m = 1; m <= 2; m <<= 1) {
        float ov = __shfl_xor(bv, m); int ok = __shfl_xor(bk, m);
        if (ov < bv || (ov == bv && ok < bk)) { bv = ov; bk = ok; }
      }
      if (slot == 0) bestk_s[row] = bk;
    }
  }
  if (tid < BM && cnt_s[tid] > CAND_CAP) {
    int p = atomicAdd(&ovf_cnt, 1);
    ovf_rows[p] = tid;
  }
  __syncthreads();

  // ====== lossless overflow fallback: block-cooperative full scan ======
  {
    const int novf = ovf_cnt;
    float* fv = (float*)cand_s;          // scratch (cand no longer needed)
    int*   fk = (int*)cand_s + 8;
    for (int i = 0; i < novf; ++i) {
      const int row = ovf_rows[i];
      const int swz = 4 * ((row >> 2) & 7);
      const float* xr = (const float*)xs4 + row * 64;
      const float xq = xsq_s[row];
      float bv = FLT_MAX; int bk = INT_MAX;
      for (int k = tid; k < K_CB; k += 256) {
        const float* er = cb + (size_t)k * D_DIM;
        float a = 0.f;
#pragma unroll 8
        for (int d = 0; d < D_DIM; ++d) a = fmaf(xr[d ^ swz], er[d], a);
        float dist = (xq + esq[k]) - 2.0f * a;
        if (dist < bv || (dist == bv && k < bk)) { bv = dist; bk = k; }
      }
#pragma unroll
      for (int m = 1; m <= 32; m <<= 1) {
        float ov = __shfl_xor(bv, m); int ok = __shfl_xor(bk, m);
        if (ov < bv || (ov == bv && ok < bk)) { bv = ov; bk = ok; }
      }
      if (lane == 0) { fv[wave] = bv; fk[wave] = bk; }
      __syncthreads();
      if (tid == 0) {
        float BV = fv[0]; int BK = fk[0];
#pragma unroll
        for (int w = 1; w < 4; ++w)
          if (fv[w] < BV || (fv[w] == BV && fk[w] < BK)) { BV = fv[w]; BK = fk[w]; }
        bestk_s[row] = BK;
      }
      __syncthreads();
    }
  }
  __syncthreads();

  // ---- gather: out[row] = codebook[bestk[row]], coalesced float4 ----
  const float4* cb4 = (const float4*)cb;
  float4* out4 = (float4*)out + (size_t)row0 * 16;
#pragma unroll
  for (int i = 0; i < 4; ++i) {
    int f = tid + i * 256;
    int row = f >> 4, c4 = f & 15;
    out4[f] = cb4[(size_t)bestk_s[row] * 16 + c4];
  }
}

extern "C" void kernel_launch(void* const* d_in, const int* in_sizes, int n_in,
                              void* d_out, int out_size, void* d_ws, size_t ws_size,
                              hipStream_t stream) {
  const float* x  = (const float*)d_in[0];   // [N, 64] fp32
  const float* cb = (const float*)d_in[1];   // [2048, 64] fp32
  float* out = (float*)d_out;                // [N, 64] fp32
  float* esq = (float*)d_ws;                 // [2048] fp32
  unsigned short* cbh = (unsigned short*)d_ws + 4096;  // bf16 codebook, 256 KB

  const int N = in_sizes[0] / D_DIM;         // 131072

  prep_kernel<<<(K_CB + 255) / 256, 256, 0, stream>>>(cb, esq, cbh);
  vq_mfma_kernel<<<N / BM, 256, 0, stream>>>(x, cb, esq, cbh, out);
}

// Round 10
// 236.521 us; speedup vs baseline: 1.8522x; 1.0106x over previous
//
#include <hip/hip_runtime.h>
#include <float.h>
#include <limits.h>

// N=131072, K=2048, D=64.
// Verified reference scheme R (rounds 5/7/8/9, absmax 0.0):
//   xsq: numpy NPY_SIMD-128 pairwise (8 vec-accs x 4 lanes + SSE3 hadd tree)
//   esq: scalar pairwise-8; dot: any fp32 order; dist=fl(fl(xsq+esq)-2dot);
//   argmin first-index.
// Round 10 = round 8's software-pipelined screen (prefetch next B-tile + esq
// one iteration ahead) WITHOUT the __launch_bounds__ min-waves clause.
// A/B/C evidence: R8's 480us regression was the forced 40-VGPR budget
// spilling the pipeline registers (FETCH 157MB/WRITE 228MB scratch traffic),
// not the pipeline itself; R9's simple loop is latency-bound (MfmaUtil 11%,
// occupancy stuck ~33% regardless of LDS headroom). Default 256-VGPR budget
// lets the prefetch live in registers: each wave tolerates full L2 latency.
#define D_DIM 64
#define K_CB  2048
#define BM    64
#define CT_PER_WAVE 32          // 16-code tiles per wave (4 waves x 512 codes)
#define MARGIN 2.5e-3f
#define CAND_CAP 32

typedef __attribute__((ext_vector_type(4))) float f32x4;
typedef __attribute__((ext_vector_type(8))) short s16x8;

__device__ __forceinline__ short f2bf(float f) {   // RN-even fp32->bf16 bits
  unsigned u = __builtin_bit_cast(unsigned, f);
  u += 0x7fffu + ((u >> 16) & 1u);
  return (short)(unsigned short)(u >> 16);
}

// prep: esq[k] (scalar-8 numpy order, verified) + bf16 codebook for MFMA
__global__ void __launch_bounds__(256) prep_kernel(const float* __restrict__ cb,
                                                   float* __restrict__ esq,
                                                   unsigned short* __restrict__ cbh) {
#pragma clang fp contract(off)
  int k = blockIdx.x * 256 + threadIdx.x;
  if (k >= K_CB) return;
  const float* row = cb + (size_t)k * D_DIM;
  float r[8];
#pragma unroll
  for (int j = 0; j < 8; ++j) { float v = row[j]; r[j] = v * v; }
#pragma unroll
  for (int i = 1; i < 8; ++i)
#pragma unroll
    for (int j = 0; j < 8; ++j) { float v = row[8 * i + j]; r[j] += v * v; }
  esq[k] = ((r[0] + r[1]) + (r[2] + r[3])) + ((r[4] + r[5]) + (r[6] + r[7]));
  unsigned short* o = cbh + (size_t)k * D_DIM;
#pragma unroll
  for (int j = 0; j < D_DIM; ++j) o[j] = (unsigned short)f2bf(row[j]);
}

__global__ void __launch_bounds__(256)
vq_mfma_kernel(const float* __restrict__ x,
               const float* __restrict__ cb,
               const float* __restrict__ esq,
               const unsigned short* __restrict__ cbh,
               float* __restrict__ out) {
#pragma clang fp contract(off)
  __shared__ float4 xs4[BM * 16];          // 16 KB x tile, float4-XOR swizzled
  __shared__ int    cand_s[BM * CAND_CAP]; // 8 KB; overlaid: rowmin (pass1),
                                           //   fallback reduce scratch (end)
  __shared__ float  xsq_s[BM];
  __shared__ float  rowthr_s[BM];
  __shared__ int    cnt_s[BM];
  __shared__ int    bestk_s[BM];
  __shared__ int    ovf_rows[BM];
  __shared__ int    ovf_cnt;

  const int tid  = threadIdx.x;
  const int lane = tid & 63;
  const int wave = tid >> 6;
  const int row0 = blockIdx.x * BM;

  // ---- stage x tile (coalesced float4), swizzle float4-col ^= (row>>2)&7 ----
  const float4* xg = (const float4*)(x + (size_t)row0 * D_DIM);
#pragma unroll
  for (int i = 0; i < 4; ++i) {
    int f = tid + i * 256;
    int row = f >> 4, c4 = f & 15;
    xs4[row * 16 + (c4 ^ ((row >> 2) & 7))] = xg[f];
  }
  if (tid == 0) ovf_cnt = 0;
  __syncthreads();

  // ---- xsq per row: numpy NPY_SIMD-128 pairwise emulation (verified R5) ----
  if (tid < BM) {
    const int swz = 4 * ((tid >> 2) & 7);
    const float* xr = (const float*)xs4 + tid * 64;
    float s[4];
#pragma unroll
    for (int l = 0; l < 4; ++l) {
      float rj[8];
#pragma unroll
      for (int j = 0; j < 8; ++j) {
        float a = xr[(4 * j + l) ^ swz];
        float b = xr[(32 + 4 * j + l) ^ swz];
        float ta = a * a;
        float tb = b * b;
        rj[j] = ta + tb;
      }
      s[l] = ((rj[0] + rj[1]) + (rj[2] + rj[3])) +
             ((rj[4] + rj[5]) + (rj[6] + rj[7]));
    }
    xsq_s[tid] = (s[0] + s[1]) + (s[2] + s[3]);
  }

  // ---- A fragments (x rows in bf16), resident in regs.  16x16x32:
  //   A: lane holds row=lane&15, k=(lane>>4)*8+j ; B: col=lane&15, same k;
  //   C: col=lane&15, row=(lane>>4)*4+reg  (m89-verified).
  s16x8 afrag[4][2];
  {
    const int arow = lane & 15;
    const int kg = (lane >> 4) * 8;
#pragma unroll
    for (int rt = 0; rt < 4; ++rt) {
      int row = rt * 16 + arow;
      int sw = (row >> 2) & 7;
#pragma unroll
      for (int kt = 0; kt < 2; ++kt) {
        int q0 = (kt * 32 + kg) >> 2;
        float4 f0 = xs4[row * 16 + (q0 ^ sw)];
        float4 f1 = xs4[row * 16 + ((q0 + 1) ^ sw)];
        s16x8 a;
        a[0] = f2bf(f0.x); a[1] = f2bf(f0.y); a[2] = f2bf(f0.z); a[3] = f2bf(f0.w);
        a[4] = f2bf(f1.x); a[5] = f2bf(f1.y); a[6] = f2bf(f1.z); a[7] = f2bf(f1.w);
        afrag[rt][kt] = a;
      }
    }
  }

  const int cbase = wave * (CT_PER_WAVE * 16);
  const int ccol = lane & 15;
  const int kgrp = (lane >> 4) * 8;

  // ================= pass 1: per-row screen min (pipelined) =================
  float minv[4][4];
#pragma unroll
  for (int rt = 0; rt < 4; ++rt)
#pragma unroll
    for (int r = 0; r < 4; ++r) minv[rt][r] = FLT_MAX;

  {
    int kbase = cbase;
    const unsigned short* bp = cbh + (size_t)(kbase + ccol) * D_DIM + kgrp;
    s16x8 b0 = *(const s16x8*)bp;
    s16x8 b1 = *(const s16x8*)(bp + 32);
    float ec = esq[kbase + ccol];
    for (int ct = 0; ct < CT_PER_WAVE; ++ct) {
      int nkbase = cbase + (((ct + 1) & (CT_PER_WAVE - 1)) << 4);
      const unsigned short* nbp = cbh + (size_t)(nkbase + ccol) * D_DIM + kgrp;
      s16x8 nb0 = *(const s16x8*)nbp;
      s16x8 nb1 = *(const s16x8*)(nbp + 32);
      float nec = esq[nkbase + ccol];
#pragma unroll
      for (int rt = 0; rt < 4; ++rt) {
        f32x4 acc = {0.f, 0.f, 0.f, 0.f};
        acc = __builtin_amdgcn_mfma_f32_16x16x32_bf16(afrag[rt][0], b0, acc, 0, 0, 0);
        acc = __builtin_amdgcn_mfma_f32_16x16x32_bf16(afrag[rt][1], b1, acc, 0, 0, 0);
#pragma unroll
        for (int r = 0; r < 4; ++r) {
          float s = fmaf(-2.0f, acc[r], ec);   // == fl(ec - 2*acc): 2*acc exact
          minv[rt][r] = fminf(minv[rt][r], s);
        }
      }
      b0 = nb0; b1 = nb1; ec = nec;
    }
  }

  // cross-lane min within the 16 cols; rowmin overlaid at front of cand_s
  float* rowmin = (float*)cand_s;        // [4 waves][BM]
#pragma unroll
  for (int rt = 0; rt < 4; ++rt)
#pragma unroll
    for (int r = 0; r < 4; ++r) {
      float v = minv[rt][r];
#pragma unroll
      for (int m = 1; m <= 8; m <<= 1) v = fminf(v, __shfl_xor(v, m));
      minv[rt][r] = v;
    }
  if ((lane & 15) == 0) {
#pragma unroll
    for (int rt = 0; rt < 4; ++rt)
#pragma unroll
      for (int r = 0; r < 4; ++r)
        rowmin[wave * BM + rt * 16 + (lane >> 4) * 4 + r] = minv[rt][r];
  }
  __syncthreads();
  if (tid < BM) {
    float m = fminf(fminf(rowmin[0 * BM + tid], rowmin[1 * BM + tid]),
                    fminf(rowmin[2 * BM + tid], rowmin[3 * BM + tid]));
    rowthr_s[tid] = m + MARGIN;
    cnt_s[tid] = 0;
  }
  __syncthreads();

  float thr[4][4];
#pragma unroll
  for (int rt = 0; rt < 4; ++rt)
#pragma unroll
    for (int r = 0; r < 4; ++r)
      thr[rt][r] = rowthr_s[rt * 16 + (lane >> 4) * 4 + r];

  // ====== pass 2: recompute (bit-identical), collect candidates ======
  {
    int kbase = cbase;
    const unsigned short* bp = cbh + (size_t)(kbase + ccol) * D_DIM + kgrp;
    s16x8 b0 = *(const s16x8*)bp;
    s16x8 b1 = *(const s16x8*)(bp + 32);
    float ec = esq[kbase + ccol];
    for (int ct = 0; ct < CT_PER_WAVE; ++ct) {
      int nkbase = cbase + (((ct + 1) & (CT_PER_WAVE - 1)) << 4);
      const unsigned short* nbp = cbh + (size_t)(nkbase + ccol) * D_DIM + kgrp;
      s16x8 nb0 = *(const s16x8*)nbp;
      s16x8 nb1 = *(const s16x8*)(nbp + 32);
      float nec = esq[nkbase + ccol];
#pragma unroll
      for (int rt = 0; rt < 4; ++rt) {
        f32x4 acc = {0.f, 0.f, 0.f, 0.f};
        acc = __builtin_amdgcn_mfma_f32_16x16x32_bf16(afrag[rt][0], b0, acc, 0, 0, 0);
        acc = __builtin_amdgcn_mfma_f32_16x16x32_bf16(afrag[rt][1], b1, acc, 0, 0, 0);
#pragma unroll
        for (int r = 0; r < 4; ++r) {
          float s = fmaf(-2.0f, acc[r], ec);
          if (s <= thr[rt][r]) {
            int row = rt * 16 + (lane >> 4) * 4 + r;
            int pos = atomicAdd(&cnt_s[row], 1);
            if (pos < CAND_CAP) cand_s[row * CAND_CAP + pos] = kbase + ccol;
          }
        }
      }
      b0 = nb0; b1 = nb1; ec = nec; kbase = nkbase;
    }
  }
  __syncthreads();

  // ====== exact rescore (R-scheme), lex-(dist,k); 4 threads per row ======
  {
    const int row = tid >> 2, slot = tid & 3;
    const int cnt = cnt_s[row];
    if (cnt <= CAND_CAP) {
      const int swz = 4 * ((row >> 2) & 7);
      const float* xr = (const float*)xs4 + row * 64;
      const float xq = xsq_s[row];
      float bv = FLT_MAX; int bk = INT_MAX;
      for (int i = slot; i < cnt; i += 4) {
        int k = cand_s[row * CAND_CAP + i];
        const float* er = cb + (size_t)k * D_DIM;
        float a = 0.f;
#pragma unroll 8
        for (int d = 0; d < D_DIM; ++d) a = fmaf(xr[d ^ swz], er[d], a);
        float dist = (xq + esq[k]) - 2.0f * a;
        if (dist < bv || (dist == bv && k < bk)) { bv = dist; bk = k; }
      }
#pragma unroll
      for (int m = 1; m <= 2; m <<= 1) {
        float ov = __shfl_xor(bv, m); int ok = __shfl_xor(bk, m);
        if (ov < bv || (ov == bv && ok < bk)) { bv = ov; bk = ok; }
      }
      if (slot == 0) bestk_s[row] = bk;
    }
  }
  if (tid < BM && cnt_s[tid] > CAND_CAP) {
    int p = atomicAdd(&ovf_cnt, 1);
    ovf_rows[p] = tid;
  }
  __syncthreads();

  // ====== lossless overflow fallback: block-cooperative full scan ======
  {
    const int novf = ovf_cnt;
    float* fv = (float*)cand_s;          // scratch (cand no longer needed)
    int*   fk = (int*)cand_s + 8;
    for (int i = 0; i < novf; ++i) {
      const int row = ovf_rows[i];
      const int swz = 4 * ((row >> 2) & 7);
      const float* xr = (const float*)xs4 + row * 64;
      const float xq = xsq_s[row];
      float bv = FLT_MAX; int bk = INT_MAX;
      for (int k = tid; k < K_CB; k += 256) {
        const float* er = cb + (size_t)k * D_DIM;
        float a = 0.f;
#pragma unroll 8
        for (int d = 0; d < D_DIM; ++d) a = fmaf(xr[d ^ swz], er[d], a);
        float dist = (xq + esq[k]) - 2.0f * a;
        if (dist < bv || (dist == bv && k < bk)) { bv = dist; bk = k; }
      }
#pragma unroll
      for (int m = 1; m <= 32; m <<= 1) {
        float ov = __shfl_xor(bv, m); int ok = __shfl_xor(bk, m);
        if (ov < bv || (ov == bv && ok < bk)) { bv = ov; bk = ok; }
      }
      if (lane == 0) { fv[wave] = bv; fk[wave] = bk; }
      __syncthreads();
      if (tid == 0) {
        float BV = fv[0]; int BK = fk[0];
#pragma unroll
        for (int w = 1; w < 4; ++w)
          if (fv[w] < BV || (fv[w] == BV && fk[w] < BK)) { BV = fv[w]; BK = fk[w]; }
        bestk_s[row] = BK;
      }
      __syncthreads();
    }
  }
  __syncthreads();

  // ---- gather: out[row] = codebook[bestk[row]], coalesced float4 ----
  const float4* cb4 = (const float4*)cb;
  float4* out4 = (float4*)out + (size_t)row0 * 16;
#pragma unroll
  for (int i = 0; i < 4; ++i) {
    int f = tid + i * 256;
    int row = f >> 4, c4 = f & 15;
    out4[f] = cb4[(size_t)bestk_s[row] * 16 + c4];
  }
}

extern "C" void kernel_launch(void* const* d_in, const int* in_sizes, int n_in,
                              void* d_out, int out_size, void* d_ws, size_t ws_size,
                              hipStream_t stream) {
  const float* x  = (const float*)d_in[0];   // [N, 64] fp32
  const float* cb = (const float*)d_in[1];   // [2048, 64] fp32
  float* out = (float*)d_out;                // [N, 64] fp32
  float* esq = (float*)d_ws;                 // [2048] fp32
  unsigned short* cbh = (unsigned short*)d_ws + 4096;  // bf16 codebook, 256 KB

  const int N = in_sizes[0] / D_DIM;         // 131072

  prep_kernel<<<(K_CB + 255) / 256, 256, 0, stream>>>(cb, esq, cbh);
  vq_mfma_kernel<<<N / BM, 256, 0, stream>>>(x, cb, esq, cbh, out);
}